// Round 8
// baseline (265.874 us; speedup 1.0000x reference)
//
#include <hip/hip_runtime.h>

// GCN3 round 8: half-wave-per-edge gather in aggL1/aggL2 (uint2/lane, 2 edge
// rows per memory instruction, shfl-combine halves) to double edge-level MLP
// in the latency-bound gathers. GEMMs: direct-A + LDS weights (r7). CSR:
// bucketed counting sort (r4). Numerics unchanged (bf16 gather, fp32 accum).

typedef __attribute__((ext_vector_type(8))) short short8;   // 8 bf16 (4 VGPR)
typedef __attribute__((ext_vector_type(4))) float f32x4;    // MFMA C/D

static __device__ __forceinline__ unsigned short f2bf(float f){
  union { float f; unsigned u; } v; v.f = f;
  unsigned r = v.u + 0x7FFF + ((v.u >> 16) & 1);            // RNE
  return (unsigned short)(r >> 16);
}
static __device__ __forceinline__ float2 bf2f2(unsigned u){
  union { unsigned u; float f; } a, b;
  a.u = u << 16; b.u = u & 0xffff0000u;
  return make_float2(a.f, b.f);
}

// ---------------- fused: edge binning + W frag-pack + x->bf16 ----------------
__global__ __launch_bounds__(256) void k_prepbin(
    const int* __restrict__ src, const int* __restrict__ dst,
    int* __restrict__ bcur, unsigned* __restrict__ pairs, int E, int binB,
    const float* __restrict__ W1, const float* __restrict__ W2,
    unsigned short* __restrict__ Wf1, unsigned short* __restrict__ Wf2,
    const float4* __restrict__ x, uint2* __restrict__ xb, int nv){
  __shared__ int cl[256];
  int blk = blockIdx.x;
  int tid = threadIdx.x;
  if (blk < binB){
    int e0 = blk * 4096 + tid;
    cl[tid] = 0; __syncthreads();
    #pragma unroll
    for (int i = 0; i < 16; i++){
      int e = e0 + i*256;
      if (e < E) atomicAdd(&cl[dst[e] >> 8], 1);
    }
    __syncthreads();
    int c = cl[tid];
    int g = (c > 0) ? atomicAdd(&bcur[tid], c) : 0;   // reserve contiguous run
    cl[tid] = g;
    __syncthreads();
    #pragma unroll
    for (int i = 0; i < 16; i++){
      int e = e0 + i*256;
      if (e < E){
        int d = dst[e];
        int b = d >> 8;
        int p = atomicAdd(&cl[b], 1);
        pairs[(b << 13) + p] = (unsigned)src[e] | ((unsigned)(d & 255) << 16);
      }
    }
  } else if (blk < binB + 256){
    int t = (blk - binB)*256 + tid;                   // 65536 pack threads
    if (t < 32768){
      // Wf1 [16 nt][4 kt][64 lane][8 j] from W1[128][256]
      int j = t & 7, lane = (t>>3) & 63, kt = (t>>9) & 3, nt = t >> 11;
      int nn = nt*16 + (lane & 15);
      int kk = kt*32 + (lane>>4)*8 + j;
      Wf1[t] = f2bf(W1[kk*256 + nn]);
    } else {
      // Wf2 [2 h][8 kt][4 ntl][64 lane][8 j] from W2[256][128]; nt = h*4+ntl
      int o = t - 32768;
      int j = o & 7, lane = (o>>3) & 63, ntl = (o>>9) & 3, kt = (o>>11) & 7, h = o >> 14;
      int nn = (h*4 + ntl)*16 + (lane & 15);
      int kk = kt*32 + (lane>>4)*8 + j;
      Wf2[o] = f2bf(W2[kk*128 + nn]);
    }
  } else {
    int i = (blk - binB - 256)*256 + tid;
    if (i < nv){
      float4 v = x[i];
      xb[i] = make_uint2((unsigned)f2bf(v.x) | ((unsigned)f2bf(v.y) << 16),
                         (unsigned)f2bf(v.z) | ((unsigned)f2bf(v.w) << 16));
    }
  }
}

// one block per bucket: node histogram + scans -> rowptr/cnt/dis + csr scatter
__global__ __launch_bounds__(256) void k_place(
    const int* __restrict__ bcur, const unsigned* __restrict__ pairs,
    unsigned short* __restrict__ csr_src, int* __restrict__ rowptr,
    int* __restrict__ cnt, float* __restrict__ dis, int n, int nb){
  __shared__ int sh[256];
  __shared__ int ncnt[256];
  int t = threadIdx.x;
  int b = blockIdx.x;
  int v = (t < nb) ? bcur[t] : 0;
  sh[t] = v; __syncthreads();
  for (int off = 1; off < 256; off <<= 1){
    int x = (t >= off) ? sh[t-off] : 0;
    __syncthreads(); sh[t] += x; __syncthreads();
  }
  int csr_base = (b == 0) ? 0 : sh[b-1];
  int cnt_b = bcur[b];
  ncnt[t] = 0; __syncthreads();
  const unsigned* P = pairs + ((size_t)b << 13);
  for (int i = t; i < cnt_b; i += 256) atomicAdd(&ncnt[P[i] >> 16], 1);
  __syncthreads();
  int c = ncnt[t];
  sh[t] = c; __syncthreads();
  for (int off = 1; off < 256; off <<= 1){
    int x = (t >= off) ? sh[t-off] : 0;
    __syncthreads(); sh[t] += x; __syncthreads();
  }
  int noff = sh[t] - c;
  int node = (b << 8) + t;
  if (node < n){
    rowptr[node] = csr_base + noff;
    cnt[node] = c;
    dis[node] = rsqrtf((float)(c + 1));           // +1 self loop
  }
  ncnt[t] = noff; __syncthreads();
  for (int i = t; i < cnt_b; i += 256){
    unsigned u = P[i];
    int p = atomicAdd(&ncnt[u >> 16], 1);
    csr_src[csr_base + p] = (unsigned short)(u & 0xffff);
  }
}

// ---------------- aggregation L1: half-wave-per-edge bf16 gather -> xa bf16 ----------------
__global__ void k_aggL1(const unsigned* __restrict__ xb, unsigned* __restrict__ out,
                        const int* __restrict__ rowptr, const int* __restrict__ cnt,
                        const unsigned short* __restrict__ csr_src,
                        const float* __restrict__ dis, int n){
  int t = threadIdx.x;
  int lane = t & 63;
  int half = lane >> 5;                 // which edge of the pair
  int col  = lane & 31;                 // uint2 (4 bf16 cols) within row
  int node = blockIdx.x*4 + (t >> 6);
  if (node >= n) return;
  const uint2* X = (const uint2*)xb;    // row stride = 32 uint2 (256 B)
  float di = dis[node];
  float4 acc;
  {
    uint2 self = X[(size_t)node*32 + col];
    float2 a = bf2f2(self.x), b = bf2f2(self.y);
    float s = half ? 0.0f : di;         // self term counted once (lower half)
    acc.x = s*a.x; acc.y = s*a.y; acc.z = s*b.x; acc.w = s*b.y;
  }
  int start = rowptr[node];
  int mm = cnt[node];
  int j = 0;
  for (; j + 15 < mm; j += 16){         // 8 pair-steps = 16 edge rows in flight
    int s[8]; float w[8]; uint2 uv[8];
    #pragma unroll
    for (int q = 0; q < 8; q++) s[q] = csr_src[start + j + 2*q + half];
    #pragma unroll
    for (int q = 0; q < 8; q++){ w[q] = dis[s[q]]; uv[q] = X[(size_t)s[q]*32 + col]; }
    #pragma unroll
    for (int q = 0; q < 8; q++){
      float2 a = bf2f2(uv[q].x), b = bf2f2(uv[q].y);
      acc.x = fmaf(w[q], a.x, acc.x); acc.y = fmaf(w[q], a.y, acc.y);
      acc.z = fmaf(w[q], b.x, acc.z); acc.w = fmaf(w[q], b.y, acc.w);
    }
  }
  for (; j + 1 < mm; j += 2){
    int s = csr_src[start + j + half];
    float w = dis[s];
    uint2 uv = X[(size_t)s*32 + col];
    float2 a = bf2f2(uv.x), b = bf2f2(uv.y);
    acc.x = fmaf(w, a.x, acc.x); acc.y = fmaf(w, a.y, acc.y);
    acc.z = fmaf(w, b.x, acc.z); acc.w = fmaf(w, b.y, acc.w);
  }
  if (j < mm){                          // odd tail: count in lower half only
    int s = csr_src[start + j];
    float w = half ? 0.0f : dis[s];
    uint2 uv = X[(size_t)s*32 + col];
    float2 a = bf2f2(uv.x), b = bf2f2(uv.y);
    acc.x = fmaf(w, a.x, acc.x); acc.y = fmaf(w, a.y, acc.y);
    acc.z = fmaf(w, b.x, acc.z); acc.w = fmaf(w, b.y, acc.w);
  }
  // combine halves (upper -> lower)
  acc.x += __shfl_down(acc.x, 32);
  acc.y += __shfl_down(acc.y, 32);
  acc.z += __shfl_down(acc.z, 32);
  acc.w += __shfl_down(acc.w, 32);
  if (half == 0){
    acc.x *= di; acc.y *= di; acc.z *= di; acc.w *= di;
    ((uint2*)out)[(size_t)node*32 + col] = make_uint2(
        (unsigned)f2bf(acc.x) | ((unsigned)f2bf(acc.y) << 16),
        (unsigned)f2bf(acc.z) | ((unsigned)f2bf(acc.w) << 16));
  }
}

// ---------------- aggregation L2: half-wave gather -> h2 fp32 (+b2,relu) + u=h2.W3 ----------------
__global__ void k_aggL2(const unsigned* __restrict__ t2b, float* __restrict__ h2,
                        const int* __restrict__ rowptr, const int* __restrict__ cnt,
                        const unsigned short* __restrict__ csr_src,
                        const float* __restrict__ dis,
                        const float* __restrict__ b2, const float* __restrict__ W3,
                        float* __restrict__ u, int n){
  int t = threadIdx.x;
  int lane = t & 63;
  int half = lane >> 5;
  int col  = lane & 31;
  int node = blockIdx.x*4 + (t >> 6);
  if (node >= n) return;
  const uint2* X = (const uint2*)t2b;
  float di = dis[node];
  float4 acc;
  {
    uint2 self = X[(size_t)node*32 + col];
    float2 a = bf2f2(self.x), b = bf2f2(self.y);
    float s = half ? 0.0f : di;
    acc.x = s*a.x; acc.y = s*a.y; acc.z = s*b.x; acc.w = s*b.y;
  }
  int start = rowptr[node];
  int mm = cnt[node];
  int j = 0;
  for (; j + 15 < mm; j += 16){
    int s[8]; float w[8]; uint2 uv[8];
    #pragma unroll
    for (int q = 0; q < 8; q++) s[q] = csr_src[start + j + 2*q + half];
    #pragma unroll
    for (int q = 0; q < 8; q++){ w[q] = dis[s[q]]; uv[q] = X[(size_t)s[q]*32 + col]; }
    #pragma unroll
    for (int q = 0; q < 8; q++){
      float2 a = bf2f2(uv[q].x), b = bf2f2(uv[q].y);
      acc.x = fmaf(w[q], a.x, acc.x); acc.y = fmaf(w[q], a.y, acc.y);
      acc.z = fmaf(w[q], b.x, acc.z); acc.w = fmaf(w[q], b.y, acc.w);
    }
  }
  for (; j + 1 < mm; j += 2){
    int s = csr_src[start + j + half];
    float w = dis[s];
    uint2 uv = X[(size_t)s*32 + col];
    float2 a = bf2f2(uv.x), b = bf2f2(uv.y);
    acc.x = fmaf(w, a.x, acc.x); acc.y = fmaf(w, a.y, acc.y);
    acc.z = fmaf(w, b.x, acc.z); acc.w = fmaf(w, b.y, acc.w);
  }
  if (j < mm){
    int s = csr_src[start + j];
    float w = half ? 0.0f : dis[s];
    uint2 uv = X[(size_t)s*32 + col];
    float2 a = bf2f2(uv.x), b = bf2f2(uv.y);
    acc.x = fmaf(w, a.x, acc.x); acc.y = fmaf(w, a.y, acc.y);
    acc.z = fmaf(w, b.x, acc.z); acc.w = fmaf(w, b.y, acc.w);
  }
  acc.x += __shfl_down(acc.x, 32);
  acc.y += __shfl_down(acc.y, 32);
  acc.z += __shfl_down(acc.z, 32);
  acc.w += __shfl_down(acc.w, 32);
  float up = 0.0f;
  if (half == 0){
    float4 b = ((const float4*)b2)[col];
    acc.x = fmaxf(fmaf(di, acc.x, b.x), 0.0f);
    acc.y = fmaxf(fmaf(di, acc.y, b.y), 0.0f);
    acc.z = fmaxf(fmaf(di, acc.z, b.z), 0.0f);
    acc.w = fmaxf(fmaf(di, acc.w, b.w), 0.0f);
    ((float4*)h2)[(size_t)node*32 + col] = acc;
    float4 w3 = ((const float4*)W3)[col];
    up = acc.x*w3.x + acc.y*w3.y + acc.z*w3.z + acc.w*w3.w;
  }
  #pragma unroll
  for (int off = 32; off > 0; off >>= 1) up += __shfl_down(up, off);
  if (lane == 0) u[node] = up;
}

// ---------------- GEMM1: xa bf16 @ W1 -> h1 fp32 (+b1,relu) + h1b bf16 ----------------
__global__ __launch_bounds__(256) void k_gemm1_mfma(
    const unsigned short* __restrict__ Xa, const unsigned short* __restrict__ Wf1,
    const float* __restrict__ bias, float* __restrict__ out,
    unsigned short* __restrict__ h1b, int n)
{
  __shared__ unsigned short Wl[8*4*64*8];   // 32 KB
  int t = threadIdx.x;
  int row0 = (blockIdx.x >> 1) * 64;
  int h = blockIdx.x & 1;
  int w = t >> 6, lane = t & 63, m = lane & 15, q = lane >> 4;
  int rbase = w*16;
  int rowm = row0 + rbase + m;
  int ra = (rowm < n) ? rowm : (n-1);       // clamp; bad rows discarded at store
  const short8* Arow = (const short8*)(Xa + (size_t)ra*128);
  short8 af[4];
  #pragma unroll
  for (int kt = 0; kt < 4; kt++) af[kt] = Arow[kt*4 + q];
  {
    const float4* src = (const float4*)Wf1 + (size_t)h*2048;
    float4* dst = (float4*)Wl;
    #pragma unroll
    for (int i = 0; i < 8; i++) dst[i*256 + t] = src[i*256 + t];
  }
  __syncthreads();
  f32x4 acc[8];
  #pragma unroll
  for (int i = 0; i < 8; i++) acc[i] = (f32x4){0.f,0.f,0.f,0.f};
  const short8* Wv = (const short8*)Wl;
  #pragma unroll
  for (int nt = 0; nt < 8; nt++){
    #pragma unroll
    for (int kt = 0; kt < 4; kt++){
      short8 bfr = Wv[(nt*4 + kt)*64 + lane];
      acc[nt] = __builtin_amdgcn_mfma_f32_16x16x32_bf16(af[kt], bfr, acc[nt], 0, 0, 0);
    }
  }
  int rowa = row0 + rbase + q*4;
  int colb = h*128 + m;
  #pragma unroll
  for (int nt = 0; nt < 8; nt++){
    float b = bias[colb + nt*16];
    #pragma unroll
    for (int r = 0; r < 4; r++){
      int rr = rowa + r;
      if (rr < n){
        float o = fmaxf(acc[nt][r] + b, 0.0f);
        out[(size_t)rr*256 + colb + nt*16] = o;
        h1b[(size_t)rr*256 + colb + nt*16] = f2bf(o);
      }
    }
  }
}

// ---------------- GEMM2: h1b bf16 @ W2 -> t2 bf16; 64 rows x 64-col half ----------------
__global__ __launch_bounds__(256) void k_gemm2_mfma(
    const unsigned short* __restrict__ H1b, const unsigned short* __restrict__ Wf2,
    unsigned short* __restrict__ T2b, int n)
{
  __shared__ unsigned short Wl[32*64*8];    // 32 KB: 8 kt x 4 ntl frags
  int t = threadIdx.x;
  int row0 = (blockIdx.x >> 1) * 64;
  int h = blockIdx.x & 1;
  int w = t >> 6, lane = t & 63, m = lane & 15, q = lane >> 4;
  int rbase = w*16;
  int rowm = row0 + rbase + m;
  int ra = (rowm < n) ? rowm : (n-1);
  const short8* Arow = (const short8*)(H1b + (size_t)ra*256);
  short8 af[8];
  #pragma unroll
  for (int kt = 0; kt < 8; kt++) af[kt] = Arow[kt*4 + q];
  {
    const float4* src = (const float4*)Wf2 + (size_t)h*2048;
    float4* dst = (float4*)Wl;
    #pragma unroll
    for (int i = 0; i < 8; i++) dst[i*256 + t] = src[i*256 + t];
  }
  __syncthreads();
  f32x4 acc[4];
  #pragma unroll
  for (int i = 0; i < 4; i++) acc[i] = (f32x4){0.f,0.f,0.f,0.f};
  const short8* Wv = (const short8*)Wl;
  #pragma unroll
  for (int nt = 0; nt < 4; nt++){
    #pragma unroll
    for (int kt = 0; kt < 8; kt++){
      short8 bfr = Wv[(kt*4 + nt)*64 + lane];
      acc[nt] = __builtin_amdgcn_mfma_f32_16x16x32_bf16(af[kt], bfr, acc[nt], 0, 0, 0);
    }
  }
  int rowa = row0 + rbase + q*4;
  #pragma unroll
  for (int nt = 0; nt < 4; nt++){
    int col = h*64 + nt*16 + m;
    #pragma unroll
    for (int r = 0; r < 4; r++){
      int rr = rowa + r;
      if (rr < n) T2b[(size_t)rr*128 + col] = f2bf(acc[nt][r]);
    }
  }
}

// ---------------- final scalar aggregation ----------------
__global__ void k_agg1d(const float* __restrict__ u, float* __restrict__ y,
                        const int* __restrict__ rowptr, const int* __restrict__ cnt,
                        const unsigned short* __restrict__ csr_src,
                        const float* __restrict__ dis,
                        const float* __restrict__ b3, int n){
  int i = blockIdx.x*256 + threadIdx.x;
  if (i >= n) return;
  float di = dis[i];
  float acc = di * u[i];
  int s0 = rowptr[i], m = cnt[i];
  for (int j = 0; j < m; j++){
    int s = csr_src[s0+j];
    acc = fmaf(dis[s], u[s], acc);
  }
  y[i] = fmaf(di, acc, b3[0]);
}

extern "C" void kernel_launch(void* const* d_in, const int* in_sizes, int n_in,
                              void* d_out, int out_size, void* d_ws, size_t ws_size,
                              hipStream_t stream){
  const float* x  = (const float*)d_in[0];
  const int*  ei  = (const int*)d_in[1];
  const float* W1 = (const float*)d_in[2];
  const float* b1 = (const float*)d_in[3];
  const float* W2 = (const float*)d_in[4];
  const float* b2 = (const float*)d_in[5];
  const float* W3 = (const float*)d_in[6];
  const float* b3 = (const float*)d_in[7];
  const int N = in_sizes[0] / 128;
  const int E = in_sizes[1] / 2;
  const int* src = ei;
  const int* dst = ei + E;
  const int NB = (N + 255) >> 8;      // 196 buckets

  char* p = (char*)d_ws;
  auto alloc = [&](size_t bytes)->char*{
    char* r = p; p += (bytes + 255) & ~(size_t)255; return r;
  };
  int*   bcur    = (int*)  alloc(256*4);
  int*   rowptr  = (int*)  alloc((size_t)N*4);
  int*   cnt     = (int*)  alloc((size_t)N*4);
  float* dis     = (float*)alloc((size_t)N*4);
  unsigned* pairs = (unsigned*)alloc((size_t)NB*8192*4);
  unsigned short* csr_src = (unsigned short*)alloc((size_t)E*2);
  unsigned* xb   = (unsigned*)alloc((size_t)N*128*2);   // bf16 x
  unsigned* xa   = (unsigned*)alloc((size_t)N*128*2);   // bf16 agg(x)
  unsigned short* h1b = (unsigned short*)alloc((size_t)N*256*2); // bf16 h1
  unsigned short* t2b = (unsigned short*)alloc((size_t)N*128*2); // bf16 h1@W2
  float* u       = (float*)alloc((size_t)N*4);
  unsigned short* wf1 = (unsigned short*)alloc(32768*2);
  unsigned short* wf2 = (unsigned short*)alloc(32768*2);

  float* y  = (float*)d_out;
  float* h1 = y + N;
  float* h2 = h1 + (size_t)N*256;

  int bb = (E + 4095)/4096;           // 196 bin blocks
  int nb = (N + 255)/256;
  int xv = N*32;                      // float4 count of x
  int xblk = (xv + 255)/256;

  hipMemsetAsync(bcur, 0, 256*4, stream);
  k_prepbin <<<bb + 256 + xblk, 256, 0, stream>>>(
      src, dst, bcur, pairs, E, bb, W1, W2, wf1, wf2,
      (const float4*)x, (uint2*)xb, xv);
  k_place   <<<NB, 256, 0, stream>>>(bcur, pairs, csr_src, rowptr, cnt, dis, N, NB);

  int ab = (N + 3)/4;
  int rb = (N + 63)/64;
  k_aggL1     <<<ab,   256, 0, stream>>>(xb, xa, rowptr, cnt, csr_src, dis, N);
  k_gemm1_mfma<<<rb*2, 256, 0, stream>>>((const unsigned short*)xa, wf1, b1, h1, h1b, N);
  k_gemm2_mfma<<<rb*2, 256, 0, stream>>>(h1b, wf2, t2b, N);
  k_aggL2     <<<ab,   256, 0, stream>>>((const unsigned*)t2b, h2, rowptr, cnt, csr_src, dis, b2, W3, u, N);
  k_agg1d     <<<nb,   256, 0, stream>>>(u, y, rowptr, cnt, csr_src, dis, b3, N);
}